// Round 2
// baseline (308.598 us; speedup 1.0000x reference)
//
#include <hip/hip_runtime.h>
#include <math.h>

#define D 128
#define NNODES 10000
#define NEDGES 16384
#define PADR 136   // padded row stride (bf16 elems)

typedef short short8 __attribute__((ext_vector_type(8)));
typedef float floatx4 __attribute__((ext_vector_type(4)));

typedef __attribute__((address_space(3))) unsigned lds_uint;
typedef __attribute__((address_space(1))) const unsigned glob_uint;

__device__ __forceinline__ void async_cp16(unsigned short* lds, const unsigned short* g) {
  __builtin_amdgcn_global_load_lds((glob_uint*)g, (lds_uint*)lds, 16, 0, 0);
}

__device__ __forceinline__ float bf2f(unsigned short u) {
  union { unsigned u; float f; } v; v.u = ((unsigned)u) << 16; return v.f;
}
__device__ __forceinline__ unsigned short f2bf(float f) {
  union { float f; unsigned u; } v; v.f = f;
  return (unsigned short)((v.u + 0x7FFFu + ((v.u >> 16) & 1u)) >> 16);
}

// K1: h = relu(edge_attr @ w1 + b1) -> hT[k][e] bf16 (row 128 = ones),
//     gather x_j -> xjb bf16 padded rows, cnt atomics.
__global__ __launch_bounds__(256) void k1_edge(
    const float* __restrict__ x, const int* __restrict__ eidx,
    const float* __restrict__ ea, const float* __restrict__ w1,
    const float* __restrict__ b1, unsigned short* __restrict__ hT,
    unsigned short* __restrict__ xjb, float* __restrict__ cnt) {
  __shared__ __align__(16) unsigned short eaL[64 * PADR];
  __shared__ __align__(16) unsigned short w1T[D * PADR];
  __shared__ int srcL[64];
  const int t = threadIdx.x;
  const int e0 = blockIdx.x * 64;
  if (t < 64) srcL[t] = eidx[e0 + t];
  if (t >= 64 && t < 128) atomicAdd(cnt + eidx[NEDGES + e0 + (t - 64)], 1.0f);
#pragma unroll 4
  for (int r = 0; r < 32; ++r) {
    int idx = r * 256 + t, e = idx >> 7, i = idx & 127;
    eaL[e * PADR + i] = f2bf(ea[(e0 + e) * D + i]);
  }
#pragma unroll 4
  for (int r = 0; r < 64; ++r) {
    int idx = r * 256 + t, i = idx >> 7, k = idx & 127;
    w1T[k * PADR + i] = f2bf(w1[i * D + k]);
  }
  __syncthreads();
#pragma unroll 4
  for (int r = 0; r < 16; ++r) {
    int idx = r * 256 + t, e = idx >> 6, i2 = (idx & 63) * 2;
    const float2 v = *(const float2*)(x + (long)srcL[e] * D + i2);
    unsigned p = (unsigned)f2bf(v.x) | ((unsigned)f2bf(v.y) << 16);
    *(unsigned*)(xjb + ((e0 + e) * PADR + i2)) = p;
  }
  const int lane = t & 63, w = t >> 6, lo = lane & 15, hi = lane >> 4;
  floatx4 acc[8];
#pragma unroll
  for (int nt = 0; nt < 8; ++nt) acc[nt] = (floatx4){0.f, 0.f, 0.f, 0.f};
#pragma unroll
  for (int ks = 0; ks < 4; ++ks) {
    const int ib = ks * 32 + hi * 8;
    const short8 af = *(const short8*)&eaL[(w * 16 + lo) * PADR + ib];
#pragma unroll
    for (int nt = 0; nt < 8; ++nt) {
      const short8 bf_ = *(const short8*)&w1T[(nt * 16 + lo) * PADR + ib];
      acc[nt] = __builtin_amdgcn_mfma_f32_16x16x32_bf16(af, bf_, acc[nt], 0, 0, 0);
    }
  }
#pragma unroll
  for (int nt = 0; nt < 8; ++nt) {
    const int ko = nt * 16 + lo;
    const float b1v = b1[ko];
    float v0 = fmaxf(acc[nt][0] + b1v, 0.f);
    float v1 = fmaxf(acc[nt][1] + b1v, 0.f);
    float v2 = fmaxf(acc[nt][2] + b1v, 0.f);
    float v3 = fmaxf(acc[nt][3] + b1v, 0.f);
    uint2 pk;
    pk.x = (unsigned)f2bf(v0) | ((unsigned)f2bf(v1) << 16);
    pk.y = (unsigned)f2bf(v2) | ((unsigned)f2bf(v3) << 16);
    *(uint2*)(hT + (ko * NEDGES + e0 + w * 16 + hi * 4)) = pk;
  }
  if (t < 64) hT[128 * NEDGES + e0 + t] = 0x3F80;  // bf16(1.0) ones-row (b2 term)
}

// K2: w2t[k][o][i] = bf16(w2[k][i*128+o]); row 128 from b2. Grid 516 = 129 k x 4 o-quarters.
__global__ __launch_bounds__(256) void k2_w2t(
    const float* __restrict__ w2, const float* __restrict__ b2,
    unsigned short* __restrict__ w2t) {
  __shared__ float L[32][129];
  const int t = threadIdx.x;
  const int k = blockIdx.x >> 2, q = blockIdx.x & 3;
  const int o0 = q * 32;
  const float* __restrict__ src = (k < D) ? (w2 + (long)k * (D * D)) : b2;
#pragma unroll
  for (int r = 0; r < 16; ++r) {
    int idx = r * 256 + t;       // 4096 = 128 i x 32 oc
    int i = idx >> 5, oc = idx & 31;
    L[oc][i] = src[i * D + o0 + oc];
  }
  __syncthreads();
  unsigned short* dst = w2t + (long)k * (D * PADR);
#pragma unroll
  for (int r = 0; r < 8; ++r) {
    int p = r * 256 + t;         // 2048 = 32 oc x 64 i2
    int oc = p >> 6, i2 = (p & 63) * 2;
    unsigned v = (unsigned)f2bf(L[oc][i2]) | ((unsigned)f2bf(L[oc][i2 + 1]) << 16);
    *(unsigned*)(dst + ((o0 + oc) * PADR + i2)) = v;
  }
}

// K3 v2: block = 128e x 128o, 4 waves (each 64o x 64e), k-chunk of ~32.
// Xj fragments k-invariant in registers; A (w2t row) double-buffered in LDS
// via async global_load_lds; single barrier per k; accumulator-side h-scale.
__global__ __launch_bounds__(256, 2) void k3_msg(
    const unsigned short* __restrict__ w2t,
    const unsigned short* __restrict__ xjb,
    const unsigned short* __restrict__ hT,
    const int* __restrict__ eidx, float* __restrict__ seg) {
  __shared__ __align__(16) unsigned short A[2][D * PADR];  // 2 x 34816 B
  __shared__ unsigned short hL[33 * 128];                  // 8448 B  (total 78080)
  const int t = threadIdx.x;
  const int b = blockIdx.x;
  // XCD swizzle: halves cluster per XCD (b%8 -> XCD): each XCD sees 1 k-range.
  const int eg = ((b >> 3) << 1) | (b & 1);   // 0..127
  const int half = (b >> 1) & 3;              // 0..3
  const int e0 = eg * 128;
  const int k0 = (half == 0) ? 0 : 33 + (half - 1) * 32;
  const int kcnt = (half == 0) ? 33 : 32;
  const int lane = t & 63, wv = t >> 6;
  const int lo = lane & 15, hi = lane >> 4;
  const int wo = (wv >> 1) * 64;   // wave o-offset
  const int we = (wv & 1) * 64;    // wave e-offset

  // stage h chunk: hL[krel*128 + e]
  for (int idx = t; idx < kcnt * 128; idx += 256)
    hL[idx] = hT[(long)(k0 + (idx >> 7)) * NEDGES + e0 + (idx & 127)];

  // preload Xj fragments (k-invariant): xf[ne][ks], 64 VGPRs
  short8 xf[4][4];
#pragma unroll
  for (int ne = 0; ne < 4; ++ne)
#pragma unroll
    for (int ks = 0; ks < 4; ++ks)
      xf[ne][ks] = *(const short8*)&xjb[(long)(e0 + we + ne * 16 + lo) * PADR + ks * 32 + hi * 8];

  // issue async stage of first A row
  {
    const unsigned short* src = w2t + (long)k0 * (D * PADR);
    for (int c = wv; c < 34; c += 4)
      async_cp16((unsigned short*)A[0] + c * 512, src + c * 512 + lane * 8);
  }

  floatx4 msg[4][4];
#pragma unroll
  for (int mo = 0; mo < 4; ++mo)
#pragma unroll
    for (int ne = 0; ne < 4; ++ne) msg[mo][ne] = (floatx4){0.f, 0.f, 0.f, 0.f};

  int cur = 0;
  for (int krel = 0; krel < kcnt; ++krel) {
    __syncthreads();  // waits vmcnt(0): A[cur] ready; prev reads of A[cur^1] drained
    if (krel + 1 < kcnt) {  // prefetch k+1 into other buffer, flies during compute
      const unsigned short* src = w2t + (long)(k0 + krel + 1) * (D * PADR);
      unsigned short* dstb = (unsigned short*)A[cur ^ 1];
      for (int c = wv; c < 34; c += 4)
        async_cp16(dstb + c * 512, src + c * 512 + lane * 8);
    }
    float hk[4];
#pragma unroll
    for (int ne = 0; ne < 4; ++ne)
      hk[ne] = bf2f(hL[krel * 128 + we + ne * 16 + lo]);
    floatx4 P[4][4];
#pragma unroll
    for (int mo = 0; mo < 4; ++mo)
#pragma unroll
      for (int ne = 0; ne < 4; ++ne) P[mo][ne] = (floatx4){0.f, 0.f, 0.f, 0.f};
#pragma unroll
    for (int ks = 0; ks < 4; ++ks) {
      const int ib = ks * 32 + hi * 8;
      short8 af[4];
#pragma unroll
      for (int mo = 0; mo < 4; ++mo)
        af[mo] = *(const short8*)&A[cur][(wo + mo * 16 + lo) * PADR + ib];
#pragma unroll
      for (int mo = 0; mo < 4; ++mo)
#pragma unroll
        for (int ne = 0; ne < 4; ++ne)
          P[mo][ne] = __builtin_amdgcn_mfma_f32_16x16x32_bf16(af[mo], xf[ne][ks], P[mo][ne], 0, 0, 0);
    }
#pragma unroll
    for (int mo = 0; mo < 4; ++mo)
#pragma unroll
      for (int ne = 0; ne < 4; ++ne)
#pragma unroll
        for (int r = 0; r < 4; ++r)
          msg[mo][ne][r] += hk[ne] * P[mo][ne][r];
    cur ^= 1;
  }
  // scatter-add: col e = lane&15 (+16*ne +we), row o = wo + mo*16 + hi*4 + r
#pragma unroll
  for (int ne = 0; ne < 4; ++ne) {
    const int node = eidx[NEDGES + e0 + we + ne * 16 + lo];
    float* base = seg + (long)node * D + wo + hi * 4;
#pragma unroll
    for (int mo = 0; mo < 4; ++mo)
#pragma unroll
      for (int r = 0; r < 4; ++r)
        atomicAdd(base + mo * 16 + r, msg[mo][ne][r]);
  }
}

// K4: out = x + gelu(seg/max(cnt,1) + x@root + bias)
__global__ __launch_bounds__(256) void k4_out(
    const float* __restrict__ x, const float* __restrict__ root,
    const float* __restrict__ bias, const float* __restrict__ seg,
    const float* __restrict__ cnt, float* __restrict__ out) {
  __shared__ __align__(16) unsigned short xL[64 * PADR];
  __shared__ __align__(16) unsigned short rT[D * PADR];
  const int t = threadIdx.x;
  const int n0 = blockIdx.x * 64;
#pragma unroll 4
  for (int r = 0; r < 32; ++r) {
    int idx = r * 256 + t, n = idx >> 7, i = idx & 127;
    float v = (n0 + n < NNODES) ? x[(long)(n0 + n) * D + i] : 0.f;
    xL[n * PADR + i] = f2bf(v);
  }
#pragma unroll 4
  for (int r = 0; r < 64; ++r) {
    int idx = r * 256 + t, ci = idx >> 7, co = idx & 127;
    rT[co * PADR + ci] = f2bf(root[ci * D + co]);
  }
  __syncthreads();
  const int lane = t & 63, w = t >> 6, lo = lane & 15, hi = lane >> 4;
  floatx4 acc[8];
#pragma unroll
  for (int nt = 0; nt < 8; ++nt) acc[nt] = (floatx4){0.f, 0.f, 0.f, 0.f};
#pragma unroll
  for (int ks = 0; ks < 4; ++ks) {
    const int ib = ks * 32 + hi * 8;
    const short8 af = *(const short8*)&xL[(w * 16 + lo) * PADR + ib];
#pragma unroll
    for (int nt = 0; nt < 8; ++nt) {
      const short8 bf_ = *(const short8*)&rT[(nt * 16 + lo) * PADR + ib];
      acc[nt] = __builtin_amdgcn_mfma_f32_16x16x32_bf16(af, bf_, acc[nt], 0, 0, 0);
    }
  }
#pragma unroll
  for (int nt = 0; nt < 8; ++nt) {
    const int co = nt * 16 + lo;
    const float bv = bias[co];
#pragma unroll
    for (int r = 0; r < 4; ++r) {
      const int n = n0 + w * 16 + hi * 4 + r;
      if (n < NNODES) {
        const float aggr = seg[(long)n * D + co] / fmaxf(cnt[n], 1.0f);
        const float v = acc[nt][r] + aggr + bv;
        const float ge = 0.5f * v * (1.0f + erff(v * 0.70710678f));
        out[(long)n * D + co] = x[(long)n * D + co] + ge;
      }
    }
  }
}

extern "C" void kernel_launch(void* const* d_in, const int* in_sizes, int n_in,
                              void* d_out, int out_size, void* d_ws, size_t ws_size,
                              hipStream_t stream) {
  (void)in_sizes; (void)n_in; (void)out_size; (void)ws_size;
  const float* x    = (const float*)d_in[0];
  const int*   eidx = (const int*)d_in[1];
  const float* ea   = (const float*)d_in[2];
  const float* w1   = (const float*)d_in[3];
  const float* b1   = (const float*)d_in[4];
  const float* w2   = (const float*)d_in[5];
  const float* b2   = (const float*)d_in[6];
  const float* root = (const float*)d_in[7];
  const float* bias = (const float*)d_in[8];
  float* out = (float*)d_out;
  char* ws = (char*)d_ws;
  // ws: hT 129*16384 bf16 @0 | xjb 16384*136 bf16 @4,227,072 |
  //     w2t 129*128*136 bf16 @8,683,520 | seg 10000*128 f32 @13,174,784 |
  //     cnt 10000 f32 @18,294,784
  unsigned short* hT  = (unsigned short*)(ws + 0);
  unsigned short* xjb = (unsigned short*)(ws + 4227072);
  unsigned short* w2t = (unsigned short*)(ws + 8683520);
  float* seg = (float*)(ws + 13174784);
  float* cnt = (float*)(ws + 18294784);
  hipMemsetAsync(ws + 13174784, 0, 5160000, stream);  // seg + cnt
  hipLaunchKernelGGL(k1_edge, dim3(NEDGES / 64), dim3(256), 0, stream,
                     x, eidx, ea, w1, b1, hT, xjb, cnt);
  hipLaunchKernelGGL(k2_w2t, dim3(516), dim3(256), 0, stream, w2, b2, w2t);
  hipLaunchKernelGGL(k3_msg, dim3(512), dim3(256), 0, stream,
                     w2t, xjb, hT, eidx, seg);
  hipLaunchKernelGGL(k4_out, dim3((NNODES + 63) / 64), dim3(256), 0, stream,
                     x, root, bias, seg, cnt, out);
}

// Round 3
// 252.945 us; speedup vs baseline: 1.2200x; 1.2200x over previous
//
#include <hip/hip_runtime.h>
#include <math.h>

#define D 128
#define NNODES 10000
#define NEDGES 16384
#define PADR 136   // padded row stride (bf16 elems); keeps 16B alignment (136*2 % 16 == 0)

typedef short short8 __attribute__((ext_vector_type(8)));
typedef float floatx4 __attribute__((ext_vector_type(4)));

typedef __attribute__((address_space(3))) unsigned lds_uint;
typedef __attribute__((address_space(1))) const unsigned glob_uint;

__device__ __forceinline__ void async_cp16(unsigned short* lds, const unsigned short* g) {
  __builtin_amdgcn_global_load_lds((glob_uint*)g, (lds_uint*)lds, 16, 0, 0);
}
__device__ __forceinline__ void async_cp4(unsigned short* lds, const unsigned short* g) {
  __builtin_amdgcn_global_load_lds((glob_uint*)g, (lds_uint*)lds, 4, 0, 0);
}

__device__ __forceinline__ float bf2f(unsigned short u) {
  union { unsigned u; float f; } v; v.u = ((unsigned)u) << 16; return v.f;
}
__device__ __forceinline__ unsigned short f2bf(float f) {
  union { float f; unsigned u; } v; v.f = f;
  return (unsigned short)((v.u + 0x7FFFu + ((v.u >> 16) & 1u)) >> 16);
}

// K1: h = relu(edge_attr @ w1 + b1) -> hT[k][e] bf16 (row 128 = ones),
//     gather x_j -> xjb bf16 padded rows, cnt atomics (float, exact ints).
__global__ __launch_bounds__(256) void k1_edge(
    const float* __restrict__ x, const int* __restrict__ eidx,
    const float* __restrict__ ea, const float* __restrict__ w1,
    const float* __restrict__ b1, unsigned short* __restrict__ hT,
    unsigned short* __restrict__ xjb, float* __restrict__ cnt) {
  __shared__ __align__(16) unsigned short eaL[64 * PADR];
  __shared__ __align__(16) unsigned short w1T[D * PADR];
  __shared__ int srcL[64];
  const int t = threadIdx.x;
  const int e0 = blockIdx.x * 64;
  if (t < 64) srcL[t] = eidx[e0 + t];
  if (t >= 64 && t < 128) atomicAdd(cnt + eidx[NEDGES + e0 + (t - 64)], 1.0f);
#pragma unroll 4
  for (int r = 0; r < 32; ++r) {
    int idx = r * 256 + t, e = idx >> 7, i = idx & 127;
    eaL[e * PADR + i] = f2bf(ea[(e0 + e) * D + i]);
  }
#pragma unroll 4
  for (int r = 0; r < 64; ++r) {
    int idx = r * 256 + t, i = idx >> 7, k = idx & 127;
    w1T[k * PADR + i] = f2bf(w1[i * D + k]);
  }
  __syncthreads();
#pragma unroll 4
  for (int r = 0; r < 16; ++r) {
    int idx = r * 256 + t, e = idx >> 6, i2 = (idx & 63) * 2;
    const float2 v = *(const float2*)(x + (long)srcL[e] * D + i2);
    unsigned p = (unsigned)f2bf(v.x) | ((unsigned)f2bf(v.y) << 16);
    *(unsigned*)(xjb + ((e0 + e) * PADR + i2)) = p;
  }
  const int lane = t & 63, w = t >> 6, lo = lane & 15, hi = lane >> 4;
  floatx4 acc[8];
#pragma unroll
  for (int nt = 0; nt < 8; ++nt) acc[nt] = (floatx4){0.f, 0.f, 0.f, 0.f};
#pragma unroll
  for (int ks = 0; ks < 4; ++ks) {
    const int ib = ks * 32 + hi * 8;
    const short8 af = *(const short8*)&eaL[(w * 16 + lo) * PADR + ib];
#pragma unroll
    for (int nt = 0; nt < 8; ++nt) {
      const short8 bf_ = *(const short8*)&w1T[(nt * 16 + lo) * PADR + ib];
      acc[nt] = __builtin_amdgcn_mfma_f32_16x16x32_bf16(af, bf_, acc[nt], 0, 0, 0);
    }
  }
#pragma unroll
  for (int nt = 0; nt < 8; ++nt) {
    const int ko = nt * 16 + lo;
    const float b1v = b1[ko];
    float v0 = fmaxf(acc[nt][0] + b1v, 0.f);
    float v1 = fmaxf(acc[nt][1] + b1v, 0.f);
    float v2 = fmaxf(acc[nt][2] + b1v, 0.f);
    float v3 = fmaxf(acc[nt][3] + b1v, 0.f);
    uint2 pk;
    pk.x = (unsigned)f2bf(v0) | ((unsigned)f2bf(v1) << 16);
    pk.y = (unsigned)f2bf(v2) | ((unsigned)f2bf(v3) << 16);
    *(uint2*)(hT + (ko * NEDGES + e0 + w * 16 + hi * 4)) = pk;
  }
  if (t < 64) hT[128 * NEDGES + e0 + t] = 0x3F80;  // bf16(1.0) ones-row (b2 term)
}

// K2: w2t[k][o][i] = bf16(w2[k][i*128+o]); row 128 from b2. Grid 516 = 129 k x 4 o-quarters.
__global__ __launch_bounds__(256) void k2_w2t(
    const float* __restrict__ w2, const float* __restrict__ b2,
    unsigned short* __restrict__ w2t) {
  __shared__ float L[32][129];
  const int t = threadIdx.x;
  const int k = blockIdx.x >> 2, q = blockIdx.x & 3;
  const int o0 = q * 32;
  const float* __restrict__ src = (k < D) ? (w2 + (long)k * (D * D)) : b2;
#pragma unroll
  for (int r = 0; r < 16; ++r) {
    int idx = r * 256 + t;       // 4096 = 128 i x 32 oc
    int i = idx >> 5, oc = idx & 31;
    L[oc][i] = src[i * D + o0 + oc];
  }
  __syncthreads();
  unsigned short* dst = w2t + (long)k * (D * PADR);
#pragma unroll
  for (int r = 0; r < 8; ++r) {
    int p = r * 256 + t;         // 2048 = 32 oc x 64 i2
    int oc = p >> 6, i2 = (p & 63) * 2;
    unsigned v = (unsigned)f2bf(L[oc][i2]) | ((unsigned)f2bf(L[oc][i2 + 1]) << 16);
    *(unsigned*)(dst + ((o0 + oc) * PADR + i2)) = v;
  }
}

// K3 v3: block = 128e x 32o, ALL 129 k. Grid 512 = 128 eg x 4 oq (XCD-swizzled).
// Xj fragments k-invariant in registers; A (32-row o-slice of w2t row k) double-
// buffered via async global_load_lds; dense float4 stores to msg (NO atomics).
__global__ __launch_bounds__(256, 3) void k3_msg(
    const unsigned short* __restrict__ w2t,
    const unsigned short* __restrict__ xjb,
    const unsigned short* __restrict__ hT,
    float* __restrict__ msgout) {
  __shared__ __align__(16) unsigned short A[2][32 * PADR];  // 2 x 8704 B
  __shared__ __align__(16) unsigned short hL[129 * 128];    // 33024 B (total 50432)
  const int t = threadIdx.x;
  const int b = blockIdx.x;
  // XCD swizzle (assume XCD = b % 8): oq fixed per XCD pair -> 1.1 MB w2t slice/XCD L2.
  const int eg = ((b >> 3) << 1) | (b & 1);   // 0..127
  const int oq = (b >> 1) & 3;                // 0..3
  const int e0 = eg * 128;
  const int o0 = oq * 32;
  const int lane = t & 63, wv = t >> 6;
  const int lo = lane & 15, hi = lane >> 4;
  const int we = (wv >> 1) * 64;   // wave e-offset (0/64)
  const int wo = (wv & 1) * 16;    // wave o-offset within 32 (0/16)

  // issue async stage of first A slice (32 rows x PADR = 4352 shorts = 8x1KB + 2x256B)
  {
    const unsigned short* src = w2t + (long)0 * (D * PADR) + o0 * PADR;
    unsigned short* dstb = (unsigned short*)A[0];
#pragma unroll
    for (int c = wv; c < 8; c += 4)
      async_cp16(dstb + c * 512, src + c * 512 + lane * 8);
    if (wv < 2)
      async_cp4(dstb + 4096 + wv * 128, src + 4096 + wv * 128 + lane * 2);
  }

  // stage hL[k][e] for all 129 k (uint2 = 4 edges per load)
  for (int idx = t; idx < 129 * 32; idx += 256) {
    int k = idx >> 5, e4 = (idx & 31) * 4;
    *(uint2*)&hL[k * 128 + e4] = *(const uint2*)&hT[(long)k * NEDGES + e0 + e4];
  }

  // preload Xj fragments (k-invariant): xf[ne][ks], 64 VGPRs
  short8 xf[4][4];
#pragma unroll
  for (int ne = 0; ne < 4; ++ne)
#pragma unroll
    for (int ks = 0; ks < 4; ++ks)
      xf[ne][ks] = *(const short8*)&xjb[(long)(e0 + we + ne * 16 + lo) * PADR + ks * 32 + hi * 8];

  floatx4 msg[4];
#pragma unroll
  for (int ne = 0; ne < 4; ++ne) msg[ne] = (floatx4){0.f, 0.f, 0.f, 0.f};

  int cur = 0;
  for (int k = 0; k < 129; ++k) {
    __syncthreads();  // drains vmcnt: A[cur] ready; prior reads of A[cur^1] done
    if (k + 1 < 129) {  // prefetch next slice into other buffer; flies during compute
      const unsigned short* src = w2t + (long)(k + 1) * (D * PADR) + o0 * PADR;
      unsigned short* dstb = (unsigned short*)A[cur ^ 1];
#pragma unroll
      for (int c = wv; c < 8; c += 4)
        async_cp16(dstb + c * 512, src + c * 512 + lane * 8);
      if (wv < 2)
        async_cp4(dstb + 4096 + wv * 128, src + 4096 + wv * 128 + lane * 2);
    }
    float hk[4];
#pragma unroll
    for (int ne = 0; ne < 4; ++ne)
      hk[ne] = bf2f(hL[k * 128 + we + ne * 16 + lo]);
    floatx4 P[4];
#pragma unroll
    for (int ne = 0; ne < 4; ++ne) P[ne] = (floatx4){0.f, 0.f, 0.f, 0.f};
#pragma unroll
    for (int ks = 0; ks < 4; ++ks) {
      const short8 af = *(const short8*)&A[cur][(wo + lo) * PADR + ks * 32 + hi * 8];
#pragma unroll
      for (int ne = 0; ne < 4; ++ne)
        P[ne] = __builtin_amdgcn_mfma_f32_16x16x32_bf16(af, xf[ne][ks], P[ne], 0, 0, 0);
    }
#pragma unroll
    for (int ne = 0; ne < 4; ++ne)
#pragma unroll
      for (int r = 0; r < 4; ++r)
        msg[ne][r] += hk[ne] * P[ne][r];
    cur ^= 1;
  }
  // dense store: row e = e0+we+ne*16+lo, cols o0+wo+hi*4 .. +4 (float4)
#pragma unroll
  for (int ne = 0; ne < 4; ++ne) {
    const long e = e0 + we + ne * 16 + lo;
    *(floatx4*)(msgout + e * D + o0 + wo + hi * 4) = msg[ne];
  }
}

// Scan: exclusive prefix over cnt -> off[0..NNODES], single block of 256.
__global__ __launch_bounds__(256) void k_scan(const float* __restrict__ cnt,
                                              int* __restrict__ off) {
  __shared__ int s[256];
  const int t = threadIdx.x;
  const int base = t * 40;  // 256*40 = 10240 >= 10000
  int sum = 0;
  for (int i = 0; i < 40; ++i) {
    int n = base + i;
    if (n < NNODES) sum += (int)cnt[n];
  }
  s[t] = sum;
  __syncthreads();
  for (int d = 1; d < 256; d <<= 1) {
    int v = (t >= d) ? s[t - d] : 0;
    __syncthreads();
    s[t] += v;
    __syncthreads();
  }
  int run = s[t] - sum;  // exclusive
  for (int i = 0; i < 40; ++i) {
    int n = base + i;
    if (n < NNODES) { off[n] = run; run += (int)cnt[n]; }
  }
  if (t == 255) off[NNODES] = run;
}

// Scatter edge ids into CSR order (int atomics only, 16K ops).
__global__ __launch_bounds__(256) void k_scatter(const int* __restrict__ eidx,
                                                 const int* __restrict__ off,
                                                 int* __restrict__ cur,
                                                 int* __restrict__ elist) {
  const int e = blockIdx.x * 256 + threadIdx.x;
  if (e < NEDGES) {
    const int d = eidx[NEDGES + e];
    const int pos = off[d] + atomicAdd(&cur[d], 1);
    elist[pos] = e;
  }
}

// K35: seg[n][o] = sum over CSR edges of msg[e][o]  (pure gather, no atomics)
__global__ __launch_bounds__(256) void k35_reduce(const float* __restrict__ msg,
                                                  const int* __restrict__ off,
                                                  const int* __restrict__ elist,
                                                  float* __restrict__ seg) {
  const int t = threadIdx.x;
  const int n = blockIdx.x * 64 + (t >> 2);
  const int oq = (t & 3) * 32;
  floatx4 a[8];
#pragma unroll
  for (int q = 0; q < 8; ++q) a[q] = (floatx4){0.f, 0.f, 0.f, 0.f};
  if (n < NNODES) {
    const int s = off[n], epos = off[n + 1];
    for (int j = s; j < epos; ++j) {
      const int e = elist[j];
      const floatx4* r = (const floatx4*)(msg + (long)e * D + oq);
#pragma unroll
      for (int q = 0; q < 8; ++q) a[q] += r[q];
    }
    floatx4* o = (floatx4*)(seg + (long)n * D + oq);
#pragma unroll
    for (int q = 0; q < 8; ++q) o[q] = a[q];
  }
}

// K4: out = x + gelu(seg/max(cnt,1) + x@root + bias)
__global__ __launch_bounds__(256) void k4_out(
    const float* __restrict__ x, const float* __restrict__ root,
    const float* __restrict__ bias, const float* __restrict__ seg,
    const float* __restrict__ cnt, float* __restrict__ out) {
  __shared__ __align__(16) unsigned short xL[64 * PADR];
  __shared__ __align__(16) unsigned short rT[D * PADR];
  const int t = threadIdx.x;
  const int n0 = blockIdx.x * 64;
#pragma unroll 4
  for (int r = 0; r < 32; ++r) {
    int idx = r * 256 + t, n = idx >> 7, i = idx & 127;
    float v = (n0 + n < NNODES) ? x[(long)(n0 + n) * D + i] : 0.f;
    xL[n * PADR + i] = f2bf(v);
  }
#pragma unroll 4
  for (int r = 0; r < 64; ++r) {
    int idx = r * 256 + t, ci = idx >> 7, co = idx & 127;
    rT[co * PADR + ci] = f2bf(root[ci * D + co]);
  }
  __syncthreads();
  const int lane = t & 63, w = t >> 6, lo = lane & 15, hi = lane >> 4;
  floatx4 acc[8];
#pragma unroll
  for (int nt = 0; nt < 8; ++nt) acc[nt] = (floatx4){0.f, 0.f, 0.f, 0.f};
#pragma unroll
  for (int ks = 0; ks < 4; ++ks) {
    const int ib = ks * 32 + hi * 8;
    const short8 af = *(const short8*)&xL[(w * 16 + lo) * PADR + ib];
#pragma unroll
    for (int nt = 0; nt < 8; ++nt) {
      const short8 bf_ = *(const short8*)&rT[(nt * 16 + lo) * PADR + ib];
      acc[nt] = __builtin_amdgcn_mfma_f32_16x16x32_bf16(af, bf_, acc[nt], 0, 0, 0);
    }
  }
#pragma unroll
  for (int nt = 0; nt < 8; ++nt) {
    const int co = nt * 16 + lo;
    const float bv = bias[co];
#pragma unroll
    for (int r = 0; r < 4; ++r) {
      const int n = n0 + w * 16 + hi * 4 + r;
      if (n < NNODES) {
        const float aggr = seg[(long)n * D + co] / fmaxf(cnt[n], 1.0f);
        const float v = acc[nt][r] + aggr + bv;
        const float ge = 0.5f * v * (1.0f + erff(v * 0.70710678f));
        out[(long)n * D + co] = x[(long)n * D + co] + ge;
      }
    }
  }
}

extern "C" void kernel_launch(void* const* d_in, const int* in_sizes, int n_in,
                              void* d_out, int out_size, void* d_ws, size_t ws_size,
                              hipStream_t stream) {
  (void)in_sizes; (void)n_in; (void)out_size; (void)ws_size;
  const float* x    = (const float*)d_in[0];
  const int*   eidx = (const int*)d_in[1];
  const float* ea   = (const float*)d_in[2];
  const float* w1   = (const float*)d_in[3];
  const float* b1   = (const float*)d_in[4];
  const float* w2   = (const float*)d_in[5];
  const float* b2   = (const float*)d_in[6];
  const float* root = (const float*)d_in[7];
  const float* bias = (const float*)d_in[8];
  float* out = (float*)d_out;
  char* ws = (char*)d_ws;
  // ws layout (bytes):
  //   hT   @ 0          : 129*16384*2      = 4,227,072
  //   xjb  @ 4,227,072  : 16384*136*2      = 4,456,448
  //   w2t  @ 8,683,520  : 129*128*136*2    = 4,491,264
  //   msg  @ 13,174,784 : 16384*128*4      = 8,388,608
  //   cnt  @ 21,563,392 : 40,000
  //   cur  @ 21,603,392 : 40,000
  //   off  @ 21,643,392 : 40,004
  //   elist@ 21,683,400 : 65,536           (total ~21.75 MB)
  //   seg  aliases hT@0 (hT dead after k3; k35 runs after k3 in stream order)
  unsigned short* hT  = (unsigned short*)(ws + 0);
  unsigned short* xjb = (unsigned short*)(ws + 4227072);
  unsigned short* w2t = (unsigned short*)(ws + 8683520);
  float* msg  = (float*)(ws + 13174784);
  float* cnt  = (float*)(ws + 21563392);
  int*   cur  = (int*)(ws + 21603392);
  int*   off  = (int*)(ws + 21643392);
  int*   elist= (int*)(ws + 21683400);
  float* seg  = (float*)(ws + 0);  // alias over hT (dead after k3)
  hipMemsetAsync(ws + 21563392, 0, 80000, stream);  // cnt + cur
  hipLaunchKernelGGL(k1_edge, dim3(NEDGES / 64), dim3(256), 0, stream,
                     x, eidx, ea, w1, b1, hT, xjb, cnt);
  hipLaunchKernelGGL(k2_w2t, dim3(516), dim3(256), 0, stream, w2, b2, w2t);
  hipLaunchKernelGGL(k_scan, dim3(1), dim3(256), 0, stream, cnt, off);
  hipLaunchKernelGGL(k_scatter, dim3(64), dim3(256), 0, stream, eidx, off, cur, elist);
  hipLaunchKernelGGL(k3_msg, dim3(512), dim3(256), 0, stream, w2t, xjb, hT, msg);
  hipLaunchKernelGGL(k35_reduce, dim3((NNODES + 63) / 64), dim3(256), 0, stream,
                     msg, off, elist, seg);
  hipLaunchKernelGGL(k4_out, dim3((NNODES + 63) / 64), dim3(256), 0, stream,
                     x, root, bias, seg, cnt, out);
}

// Round 4
// 213.557 us; speedup vs baseline: 1.4450x; 1.1844x over previous
//
#include <hip/hip_runtime.h>
#include <math.h>

#define D 128
#define NNODES 10000
#define NEDGES 16384
#define PADR 136   // padded row stride (bf16): 272B rows -> b128 LDS reads ~bank-balanced

typedef short short8 __attribute__((ext_vector_type(8)));
typedef float floatx4 __attribute__((ext_vector_type(4)));

typedef __attribute__((address_space(3))) unsigned lds_uint;
typedef __attribute__((address_space(1))) const unsigned glob_uint;

__device__ __forceinline__ void async_cp16(unsigned short* lds, const unsigned short* g) {
  __builtin_amdgcn_global_load_lds((glob_uint*)g, (lds_uint*)lds, 16, 0, 0);
}
__device__ __forceinline__ void async_cp4(unsigned short* lds, const unsigned short* g) {
  __builtin_amdgcn_global_load_lds((glob_uint*)g, (lds_uint*)lds, 4, 0, 0);
}

__device__ __forceinline__ float bf2f(unsigned short u) {
  union { unsigned u; float f; } v; v.u = ((unsigned)u) << 16; return v.f;
}
__device__ __forceinline__ unsigned short f2bf(float f) {
  union { float f; unsigned u; } v; v.f = f;
  return (unsigned short)((v.u + 0x7FFFu + ((v.u >> 16) & 1u)) >> 16);
}
__device__ __forceinline__ short8 pack8(float4 a, float4 b) {
  short8 r;
  r[0] = (short)f2bf(a.x); r[1] = (short)f2bf(a.y);
  r[2] = (short)f2bf(a.z); r[3] = (short)f2bf(a.w);
  r[4] = (short)f2bf(b.x); r[5] = (short)f2bf(b.y);
  r[6] = (short)f2bf(b.z); r[7] = (short)f2bf(b.w);
  return r;
}

// K2/prep: transpose+convert weights once.
//   bid<516 : w2t[k][o][i] = bf16(w2[k][i*128+o]) (k==128 -> b2), quarters of 32 o
//   516..519: w1t[k][i]   = bf16(w1[i*128+k])
//   520..523: rootT[co][ci]= bf16(root[ci*128+co])
__global__ __launch_bounds__(256) void k2_prep(
    const float* __restrict__ w2, const float* __restrict__ b2,
    const float* __restrict__ w1, const float* __restrict__ root,
    unsigned short* __restrict__ w2t, unsigned short* __restrict__ w1t,
    unsigned short* __restrict__ rootT) {
  __shared__ float L[32][129];
  const int t = threadIdx.x;
  const int bid = blockIdx.x;
  const float* __restrict__ src;
  unsigned short* dst;
  int o0;
  if (bid < 516) {
    const int k = bid >> 2;
    o0 = (bid & 3) * 32;
    src = (k < D) ? (w2 + (long)k * (D * D)) : b2;
    dst = w2t + (long)k * (D * PADR);
  } else if (bid < 520) {
    o0 = (bid - 516) * 32; src = w1; dst = w1t;
  } else {
    o0 = (bid - 520) * 32; src = root; dst = rootT;
  }
#pragma unroll
  for (int r = 0; r < 16; ++r) {
    int idx = r * 256 + t;       // 4096 = 128 i x 32 oc
    int i = idx >> 5, oc = idx & 31;
    L[oc][i] = src[i * D + o0 + oc];
  }
  __syncthreads();
#pragma unroll
  for (int r = 0; r < 8; ++r) {
    int p = r * 256 + t;         // 2048 = 32 oc x 64 i2
    int oc = p >> 6, i2 = (p & 63) * 2;
    unsigned v = (unsigned)f2bf(L[oc][i2]) | ((unsigned)f2bf(L[oc][i2 + 1]) << 16);
    *(unsigned*)(dst + ((o0 + oc) * PADR + i2)) = v;
  }
}

// K1: h = relu(ea @ w1 + b1) -> hT[k][e] (row 128 = ones); x_j gather -> xjb;
// cnt int atomics. No LDS, no barriers: A-frag from ea (f32->bf16 in regs),
// B-frag direct from w1t (bf16, L2-hot).
__global__ __launch_bounds__(256) void k1_edge(
    const float* __restrict__ x, const int* __restrict__ eidx,
    const float* __restrict__ ea, const unsigned short* __restrict__ w1t,
    const float* __restrict__ b1, unsigned short* __restrict__ hT,
    unsigned short* __restrict__ xjb, int* __restrict__ cnt) {
  const int t = threadIdx.x;
  const int e0 = blockIdx.x * 64;
  if (t < 64) atomicAdd(&cnt[eidx[NEDGES + e0 + t]], 1);
#pragma unroll 4
  for (int r = 0; r < 16; ++r) {
    int idx = r * 256 + t, e = idx >> 6, i2 = (idx & 63) * 2;
    const int s = eidx[e0 + e];
    const float2 v = *(const float2*)(x + (long)s * D + i2);
    unsigned p = (unsigned)f2bf(v.x) | ((unsigned)f2bf(v.y) << 16);
    *(unsigned*)(xjb + ((e0 + e) * PADR + i2)) = p;
  }
  const int lane = t & 63, w = t >> 6, lo = lane & 15, hi = lane >> 4;
  short8 af[4];
#pragma unroll
  for (int ks = 0; ks < 4; ++ks) {
    const float* p0 = ea + (long)(e0 + w * 16 + lo) * D + ks * 32 + hi * 8;
    af[ks] = pack8(*(const float4*)p0, *(const float4*)(p0 + 4));
  }
  floatx4 acc[8];
#pragma unroll
  for (int nt = 0; nt < 8; ++nt) acc[nt] = (floatx4){0.f, 0.f, 0.f, 0.f};
#pragma unroll
  for (int ks = 0; ks < 4; ++ks) {
    const int ib = ks * 32 + hi * 8;
#pragma unroll
    for (int nt = 0; nt < 8; ++nt) {
      const short8 bf_ = *(const short8*)&w1t[(nt * 16 + lo) * PADR + ib];
      acc[nt] = __builtin_amdgcn_mfma_f32_16x16x32_bf16(af[ks], bf_, acc[nt], 0, 0, 0);
    }
  }
#pragma unroll
  for (int nt = 0; nt < 8; ++nt) {
    const int ko = nt * 16 + lo;
    const float b1v = b1[ko];
    float v0 = fmaxf(acc[nt][0] + b1v, 0.f);
    float v1 = fmaxf(acc[nt][1] + b1v, 0.f);
    float v2 = fmaxf(acc[nt][2] + b1v, 0.f);
    float v3 = fmaxf(acc[nt][3] + b1v, 0.f);
    uint2 pk;
    pk.x = (unsigned)f2bf(v0) | ((unsigned)f2bf(v1) << 16);
    pk.y = (unsigned)f2bf(v2) | ((unsigned)f2bf(v3) << 16);
    *(uint2*)(hT + (ko * NEDGES + e0 + w * 16 + hi * 4)) = pk;
  }
  if (t < 64) hT[128 * NEDGES + e0 + t] = 0x3F80;  // bf16(1.0) ones-row (b2 term)
}

// K3 v4: block = 128e x 32o, all 129 k in 33 phases of 4 k (last=1).
// Per phase: one barrier; A 4-slice double-buffered via async global_load_lds
// (wave wv stages slice wv); h slice double-buffered via regs->ds_write.
// 256 MFMA/block/phase -> prefetch latency fully hidden.
__global__ __launch_bounds__(256, 2) void k3_msg(
    const unsigned short* __restrict__ w2t,
    const unsigned short* __restrict__ xjb,
    const unsigned short* __restrict__ hT,
    float* __restrict__ msgout) {
  __shared__ __align__(16) unsigned short A[2][4][32 * PADR];  // 69,632 B
  __shared__ unsigned short hC[2][4 * 128];                    //  2,048 B
  const int t = threadIdx.x;
  const int b = blockIdx.x;
  const int eg = ((b >> 3) << 1) | (b & 1);   // 0..127
  const int oq = (b >> 1) & 3;                // fixed per XCD -> L2 locality
  const int e0 = eg * 128;
  const int o0 = oq * 32;
  const int lane = t & 63, wv = t >> 6;
  const int lo = lane & 15, hi = lane >> 4;
  const int we = (wv >> 1) * 64;   // wave e-offset (0/64)
  const int wo = (wv & 1) * 16;    // wave o-offset within 32 (0/16)
  const int hr = t >> 6, he2 = t & 63;  // h staging coords (row, dword)

  // preload Xj fragments (k-invariant): 64 VGPRs
  short8 xf[4][4];
#pragma unroll
  for (int ne = 0; ne < 4; ++ne)
#pragma unroll
    for (int ks = 0; ks < 4; ++ks)
      xf[ne][ks] = *(const short8*)&xjb[(long)(e0 + we + ne * 16 + lo) * PADR + ks * 32 + hi * 8];

  // prime phase 0: A slices 0..3 (one per wave), h rows 0..3
  {
    const unsigned short* src = w2t + (long)wv * (D * PADR) + o0 * PADR;
    unsigned short* dstb = (unsigned short*)&A[0][wv][0];
#pragma unroll
    for (int c = 0; c < 8; ++c)
      async_cp16(dstb + c * 512, src + c * 512 + lane * 8);
#pragma unroll
    for (int c = 0; c < 2; ++c)
      async_cp4(dstb + 4096 + c * 128, src + 4096 + c * 128 + lane * 2);
    const unsigned hv0 = *(const unsigned*)&hT[(long)hr * NEDGES + e0 + he2 * 2];
    *(unsigned*)&hC[0][hr * 128 + he2 * 2] = hv0;
  }

  floatx4 msg[4];
#pragma unroll
  for (int ne = 0; ne < 4; ++ne) msg[ne] = (floatx4){0.f, 0.f, 0.f, 0.f};

  int cur = 0;
  for (int p = 0; p < 33; ++p) {
    const int kc = (p < 32) ? 4 : 1;
    __syncthreads();  // vmcnt+lgkm drain: A[cur], hC[cur] ready; A[cur^1] reads done
    const int kbn = (p + 1) * 4;
    const int kcn = (p < 32) ? ((p < 31) ? 4 : 1) : 0;
    // prefetch next phase A (async -> other buffer)
    if (wv < kcn) {
      const unsigned short* src = w2t + (long)(kbn + wv) * (D * PADR) + o0 * PADR;
      unsigned short* dstb = (unsigned short*)&A[cur ^ 1][wv][0];
#pragma unroll
      for (int c = 0; c < 8; ++c)
        async_cp16(dstb + c * 512, src + c * 512 + lane * 8);
#pragma unroll
      for (int c = 0; c < 2; ++c)
        async_cp4(dstb + 4096 + c * 128, src + 4096 + c * 128 + lane * 2);
    }
    // prefetch next phase h into regs
    unsigned hv = 0;
    if (hr < kcn) hv = *(const unsigned*)&hT[(long)(kbn + hr) * NEDGES + e0 + he2 * 2];

    // compute kc k's from A[cur] / hC[cur]
    auto body = [&](int kk) {
      float hk[4];
#pragma unroll
      for (int ne = 0; ne < 4; ++ne)
        hk[ne] = bf2f(hC[cur][kk * 128 + we + ne * 16 + lo]);
      floatx4 P[4];
#pragma unroll
      for (int ne = 0; ne < 4; ++ne) P[ne] = (floatx4){0.f, 0.f, 0.f, 0.f};
#pragma unroll
      for (int ks = 0; ks < 4; ++ks) {
        const short8 a = *(const short8*)&A[cur][kk][(wo + lo) * PADR + ks * 32 + hi * 8];
#pragma unroll
        for (int ne = 0; ne < 4; ++ne)
          P[ne] = __builtin_amdgcn_mfma_f32_16x16x32_bf16(a, xf[ne][ks], P[ne], 0, 0, 0);
      }
#pragma unroll
      for (int ne = 0; ne < 4; ++ne)
#pragma unroll
        for (int r = 0; r < 4; ++r)
          msg[ne][r] += hk[ne] * P[ne][r];
    };
    if (kc == 4) {
#pragma unroll
      for (int kk = 0; kk < 4; ++kk) body(kk);
    } else {
      body(0);
    }
    // store next-phase h into other buffer (visible after next barrier)
    if (hr < kcn) *(unsigned*)&hC[cur ^ 1][hr * 128 + he2 * 2] = hv;
    cur ^= 1;
  }
  // dense store: row e = e0+we+ne*16+lo, cols o0+wo+hi*4 (float4)
#pragma unroll
  for (int ne = 0; ne < 4; ++ne) {
    const long e = e0 + we + ne * 16 + lo;
    *(floatx4*)(msgout + e * D + o0 + wo + hi * 4) = msg[ne];
  }
}

// Scan: exclusive prefix over cnt -> off[0..NNODES], single block.
__global__ __launch_bounds__(256) void k_scan(const int* __restrict__ cnt,
                                              int* __restrict__ off) {
  __shared__ int s[256];
  const int t = threadIdx.x;
  const int base = t * 40;
  int sum = 0;
#pragma unroll 8
  for (int i = 0; i < 40; ++i) {
    int n = base + i;
    if (n < NNODES) sum += cnt[n];
  }
  s[t] = sum;
  __syncthreads();
  for (int d = 1; d < 256; d <<= 1) {
    int v = (t >= d) ? s[t - d] : 0;
    __syncthreads();
    s[t] += v;
    __syncthreads();
  }
  int run = s[t] - sum;
  for (int i = 0; i < 40; ++i) {
    int n = base + i;
    if (n < NNODES) { off[n] = run; run += cnt[n]; }
  }
  if (t == 255) off[NNODES] = run;
}

// Scatter edge ids into CSR order (16K int atomics).
__global__ __launch_bounds__(256) void k_scatter(const int* __restrict__ eidx,
                                                 const int* __restrict__ off,
                                                 int* __restrict__ cur,
                                                 int* __restrict__ elist) {
  const int e = blockIdx.x * 256 + threadIdx.x;
  if (e < NEDGES) {
    const int d = eidx[NEDGES + e];
    const int pos = off[d] + atomicAdd(&cur[d], 1);
    elist[pos] = e;
  }
}

// K35: seg[n][o] = sum over CSR edges of msg[e][o] (pure gather).
__global__ __launch_bounds__(256) void k35_reduce(const float* __restrict__ msg,
                                                  const int* __restrict__ off,
                                                  const int* __restrict__ elist,
                                                  float* __restrict__ seg) {
  const int t = threadIdx.x;
  const int n = blockIdx.x * 64 + (t >> 2);
  const int oq = (t & 3) * 32;
  floatx4 a[8];
#pragma unroll
  for (int q = 0; q < 8; ++q) a[q] = (floatx4){0.f, 0.f, 0.f, 0.f};
  if (n < NNODES) {
    const int s = off[n], epos = off[n + 1];
    for (int j = s; j < epos; ++j) {
      const int e = elist[j];
      const floatx4* r = (const floatx4*)(msg + (long)e * D + oq);
#pragma unroll
      for (int q = 0; q < 8; ++q) a[q] += r[q];
    }
    floatx4* o = (floatx4*)(seg + (long)n * D + oq);
#pragma unroll
    for (int q = 0; q < 8; ++q) o[q] = a[q];
  }
}

// K4: out = x + gelu(seg/max(cnt,1) + x@root + bias). No LDS/barriers.
__global__ __launch_bounds__(256) void k4_out(
    const float* __restrict__ x, const unsigned short* __restrict__ rootT,
    const float* __restrict__ bias, const float* __restrict__ seg,
    const int* __restrict__ cnt, float* __restrict__ out) {
  const int t = threadIdx.x;
  const int n0 = blockIdx.x * 64;
  const int lane = t & 63, w = t >> 6, lo = lane & 15, hi = lane >> 4;
  const int nrow = n0 + w * 16 + lo;
  short8 af[4];
#pragma unroll
  for (int ks = 0; ks < 4; ++ks) {
    if (nrow < NNODES) {
      const float* p0 = x + (long)nrow * D + ks * 32 + hi * 8;
      af[ks] = pack8(*(const float4*)p0, *(const float4*)(p0 + 4));
    } else {
      af[ks] = (short8){0, 0, 0, 0, 0, 0, 0, 0};
    }
  }
  floatx4 acc[8];
#pragma unroll
  for (int nt = 0; nt < 8; ++nt) acc[nt] = (floatx4){0.f, 0.f, 0.f, 0.f};
#pragma unroll
  for (int ks = 0; ks < 4; ++ks) {
    const int ib = ks * 32 + hi * 8;
#pragma unroll
    for (int nt = 0; nt < 8; ++nt) {
      const short8 bf_ = *(const short8*)&rootT[(nt * 16 + lo) * PADR + ib];
      acc[nt] = __builtin_amdgcn_mfma_f32_16x16x32_bf16(af[ks], bf_, acc[nt], 0, 0, 0);
    }
  }
#pragma unroll
  for (int nt = 0; nt < 8; ++nt) {
    const int co = nt * 16 + lo;
    const float bv = bias[co];
#pragma unroll
    for (int r = 0; r < 4; ++r) {
      const int n = n0 + w * 16 + hi * 4 + r;
      if (n < NNODES) {
        const float aggr = seg[(long)n * D + co] / fmaxf((float)cnt[n], 1.0f);
        const float v = acc[nt][r] + aggr + bv;
        const float ge = 0.5f * v * (1.0f + erff(v * 0.70710678f));
        out[(long)n * D + co] = x[(long)n * D + co] + ge;
      }
    }
  }
}

extern "C" void kernel_launch(void* const* d_in, const int* in_sizes, int n_in,
                              void* d_out, int out_size, void* d_ws, size_t ws_size,
                              hipStream_t stream) {
  (void)in_sizes; (void)n_in; (void)out_size; (void)ws_size;
  const float* x    = (const float*)d_in[0];
  const int*   eidx = (const int*)d_in[1];
  const float* ea   = (const float*)d_in[2];
  const float* w1   = (const float*)d_in[3];
  const float* b1   = (const float*)d_in[4];
  const float* w2   = (const float*)d_in[5];
  const float* b2   = (const float*)d_in[6];
  const float* root = (const float*)d_in[7];
  const float* bias = (const float*)d_in[8];
  float* out = (float*)d_out;
  char* ws = (char*)d_ws;
  // ws layout (bytes):
  //   hT    @ 0          : 4,227,072
  //   xjb   @ 4,227,072  : 4,456,448
  //   w2t   @ 8,683,520  : 4,491,264
  //   msg   @ 13,174,784 : 8,388,608
  //   cnt   @ 21,563,392 : 40,000 (int)
  //   cur   @ 21,603,392 : 40,000
  //   off   @ 21,643,392 : 40,004
  //   elist @ 21,683,400 : 65,536
  //   w1t   @ 21,748,992 : 34,816
  //   rootT @ 21,783,808 : 34,816   (total ~21.82 MB)
  //   seg aliases @0 (hT/xjb dead after k3)
  unsigned short* hT    = (unsigned short*)(ws + 0);
  unsigned short* xjb   = (unsigned short*)(ws + 4227072);
  unsigned short* w2t   = (unsigned short*)(ws + 8683520);
  float*          msg   = (float*)(ws + 13174784);
  int*            cnt   = (int*)(ws + 21563392);
  int*            cur   = (int*)(ws + 21603392);
  int*            off   = (int*)(ws + 21643392);
  int*            elist = (int*)(ws + 21683400);
  unsigned short* w1t   = (unsigned short*)(ws + 21748992);
  unsigned short* rootT = (unsigned short*)(ws + 21783808);
  float*          seg   = (float*)(ws + 0);
  hipMemsetAsync(ws + 21563392, 0, 80000, stream);  // cnt + cur
  hipLaunchKernelGGL(k2_prep, dim3(524), dim3(256), 0, stream,
                     w2, b2, w1, root, w2t, w1t, rootT);
  hipLaunchKernelGGL(k1_edge, dim3(NEDGES / 64), dim3(256), 0, stream,
                     x, eidx, ea, w1t, b1, hT, xjb, cnt);
  hipLaunchKernelGGL(k_scan, dim3(1), dim3(256), 0, stream, cnt, off);
  hipLaunchKernelGGL(k_scatter, dim3(64), dim3(256), 0, stream, eidx, off, cur, elist);
  hipLaunchKernelGGL(k3_msg, dim3(512), dim3(256), 0, stream, w2t, xjb, hT, msg);
  hipLaunchKernelGGL(k35_reduce, dim3((NNODES + 63) / 64), dim3(256), 0, stream,
                     msg, off, elist, seg);
  hipLaunchKernelGGL(k4_out, dim3((NNODES + 63) / 64), dim3(256), 0, stream,
                     x, rootT, bias, seg, cnt, out);
}